// Round 2
// baseline (775.820 us; speedup 1.0000x reference)
//
#include <hip/hip_runtime.h>
#include <math.h>

// Problem constants (shapes follow the reference; N and E derived from in_sizes)
#define DIMX   256
#define HEADS  16
#define QKD    8
#define DH     128           // HEADS*QKD
#define QKVW   512           // 2*DH + DIMX
#define INRPE  18
#define SCALE  0.35355339059327373f   // 8^-0.5

// ---------------------------------------------------------------------------
// Kernel 1: qkv = x @ Wqkv + b ; store with q-part pre-scaled by SCALE.
// Layout per node row (512 floats): [q*SCALE (128) | k (128) | v (256)]
// 128x64 tile, 256 threads, 8x4 microtile.
// ---------------------------------------------------------------------------
__global__ __launch_bounds__(256) void qkv_gemm(
    const float* __restrict__ x, const float* __restrict__ W,
    const float* __restrict__ bias, float* __restrict__ qkv, int Nn)
{
    __shared__ float As[16][132];   // A^T tile, row stride 132 floats
    __shared__ float Bs[16][64];

    int tid  = threadIdx.x;
    int row0 = blockIdx.x * 128;
    int col0 = blockIdx.y * 64;
    int tx = tid & 15, ty = tid >> 4;

    float acc[8][4] = {};

    for (int k0 = 0; k0 < DIMX; k0 += 16) {
        // A tile: 128 rows x 16 cols = 512 float4 loads, 2 per thread
        #pragma unroll
        for (int r = 0; r < 2; r++) {
            int idx  = tid + r * 256;
            int arow = idx >> 2, acol = (idx & 3) * 4;
            float4 av = make_float4(0.f, 0.f, 0.f, 0.f);
            int grow = row0 + arow;
            if (grow < Nn) av = *(const float4*)&x[(size_t)grow * DIMX + k0 + acol];
            As[acol + 0][arow] = av.x;
            As[acol + 1][arow] = av.y;
            As[acol + 2][arow] = av.z;
            As[acol + 3][arow] = av.w;
        }
        // B tile: 16 rows x 64 cols
        {
            int brow = tid >> 4, bcol = (tid & 15) * 4;
            float4 bv = *(const float4*)&W[(size_t)(k0 + brow) * QKVW + col0 + bcol];
            *(float4*)&Bs[brow][bcol] = bv;
        }
        __syncthreads();
        #pragma unroll
        for (int kk = 0; kk < 16; kk++) {
            float a0[8], b0[4];
            *(float4*)&a0[0] = *(const float4*)&As[kk][ty * 8];
            *(float4*)&a0[4] = *(const float4*)&As[kk][ty * 8 + 4];
            *(float4*)&b0[0] = *(const float4*)&Bs[kk][tx * 4];
            #pragma unroll
            for (int i = 0; i < 8; i++)
                #pragma unroll
                for (int j = 0; j < 4; j++)
                    acc[i][j] = fmaf(a0[i], b0[j], acc[i][j]);
        }
        __syncthreads();
    }

    // epilogue: add bias, scale q-columns, store
    float4 bv = *(const float4*)&bias[col0 + tx * 4];
    float sc = (col0 + tx * 4) < DH ? SCALE : 1.0f;  // col0 multiple of 64 -> whole tile same side
    #pragma unroll
    for (int i = 0; i < 8; i++) {
        int grow = row0 + ty * 8 + i;
        if (grow < Nn) {
            float4 o;
            o.x = (acc[i][0] + bv.x) * sc;
            o.y = (acc[i][1] + bv.y) * sc;
            o.z = (acc[i][2] + bv.z) * sc;
            o.w = (acc[i][3] + bv.w) * sc;
            *(float4*)&qkv[(size_t)grow * QKVW + col0 + tx * 4] = o;
        }
    }
}

// ---------------------------------------------------------------------------
// CSR build: count -> scan -> scatter (grouped by source node s)
// edge_index arrives as int32 (harness converts integer inputs to int).
// ---------------------------------------------------------------------------
__global__ void count_kernel(const int* __restrict__ ei, int* __restrict__ deg, int E)
{
    int e = blockIdx.x * blockDim.x + threadIdx.x;
    if (e < E) atomicAdd(&deg[ei[e]], 1);
}

__global__ __launch_bounds__(1024) void scan_kernel(
    const int* __restrict__ deg, int* __restrict__ off, int n)
{
    __shared__ int part[1024];
    int tid = threadIdx.x;
    int chunk = (n + 1023) / 1024;
    int s = tid * chunk;
    int epos = min(s + chunk, n);
    int sum = 0;
    for (int i = s; i < epos; i++) sum += deg[i];
    part[tid] = sum;
    __syncthreads();
    for (int d = 1; d < 1024; d <<= 1) {
        int v = (tid >= d) ? part[tid - d] : 0;
        __syncthreads();
        part[tid] += v;
        __syncthreads();
    }
    int run = part[tid] - sum;   // exclusive base
    for (int i = s; i < epos; i++) { off[i] = run; run += deg[i]; }
    if (tid == 1023) off[n] = run;
}

__global__ void scatter_kernel(const int* __restrict__ ei,
                               const int* __restrict__ off, int* __restrict__ cur,
                               int2* __restrict__ elist, int E)
{
    int e = blockIdx.x * blockDim.x + threadIdx.x;
    if (e < E) {
        int s = ei[e];
        int t = ei[E + e];
        int pos = atomicAdd(&cur[s], 1);
        elist[off[s] + pos] = make_int2(e, t);
    }
}

// ---------------------------------------------------------------------------
// Kernel 2: node-centric fused attention. One wave (64 lanes) per node.
// Lane l -> head h = l>>2, dim-pair dp = l&3 (qk dims 2l, 2l+1 of flat 128).
// Per edge: RPE (weights resident in 72 VGPRs), compat dot + quad shuffle-
// reduce, online softmax, v-gather float4, register accumulation. Single
// coalesced float4 row write at the end. No float atomics anywhere.
// ---------------------------------------------------------------------------
__global__ __launch_bounds__(256) void node_attn(
    const float* __restrict__ qkv, const int2* __restrict__ elist,
    const int* __restrict__ off, const float* __restrict__ edge_attr,
    const float* __restrict__ Wq_rpe, const float* __restrict__ bq_rpe,
    const float* __restrict__ Wk_rpe, const float* __restrict__ bk_rpe,
    float* __restrict__ out, int Nn)
{
    int wave = threadIdx.x >> 6;
    int lane = threadIdx.x & 63;
    int n = blockIdx.x * 4 + wave;
    if (n >= Nn) return;

    int c0 = lane * 2;

    // resident RPE weight columns for this lane's two qk dims
    float wq0[INRPE], wq1[INRPE], wk0[INRPE], wk1[INRPE];
    #pragma unroll
    for (int j = 0; j < INRPE; j++) {
        wq0[j] = Wq_rpe[j * DH + c0];
        wq1[j] = Wq_rpe[j * DH + c0 + 1];
        wk0[j] = Wk_rpe[j * DH + c0];
        wk1[j] = Wk_rpe[j * DH + c0 + 1];
    }
    float bq0 = bq_rpe[c0], bq1 = bq_rpe[c0 + 1];
    float bk0 = bk_rpe[c0], bk1 = bk_rpe[c0 + 1];

    // this node's (pre-scaled) q for the lane's two dims
    float qs0 = qkv[(size_t)n * QKVW + c0];
    float qs1 = qkv[(size_t)n * QKVW + c0 + 1];

    int beg = off[n], end = off[n + 1];

    float m = -INFINITY, lsum = 0.0f;
    float4 o = make_float4(0.f, 0.f, 0.f, 0.f);

    for (int i = beg; i < end; i++) {
        int2 et = elist[i];
        int e = et.x, t = et.y;

        // edge_attr[e][0..17] (wave-uniform broadcast loads)
        const float2* ea2 = (const float2*)(edge_attr + (size_t)e * INRPE);
        float a[INRPE];
        #pragma unroll
        for (int j = 0; j < 9; j++) {
            float2 v = ea2[j];
            a[2 * j] = v.x;
            a[2 * j + 1] = v.y;
        }

        // RPE projections for this lane's two dims (q and k)
        float qr0 = bq0, qr1 = bq1, kr0 = bk0, kr1 = bk1;
        #pragma unroll
        for (int j = 0; j < INRPE; j++) {
            qr0 = fmaf(a[j], wq0[j], qr0);
            qr1 = fmaf(a[j], wq1[j], qr1);
            kr0 = fmaf(a[j], wk0[j], kr0);
            kr1 = fmaf(a[j], wk1[j], kr1);
        }

        // gather k[t] (two dims, coalesced float2 across the wave: 512B)
        float2 kt = *(const float2*)&qkv[(size_t)t * QKVW + DH + c0];

        float c2 = (qs0 + qr0) * (kt.x + kr0) + (qs1 + qr1) * (kt.y + kr1);
        // reduce over the 4 lanes of this head
        c2 += __shfl_xor(c2, 1, 64);
        c2 += __shfl_xor(c2, 2, 64);

        // online softmax update
        float mn = fmaxf(m, c2);
        float alpha = __expf(m - mn);     // first edge: exp(-inf)=0
        float ex = __expf(c2 - mn);
        lsum = lsum * alpha + ex;

        // gather v[t]: lane's 4 output dims (head l>>2), coalesced 1KB row
        float4 vt = *(const float4*)&qkv[(size_t)t * QKVW + 2 * DH + 4 * lane];
        o.x = fmaf(ex, vt.x, o.x * alpha);
        o.y = fmaf(ex, vt.y, o.y * alpha);
        o.z = fmaf(ex, vt.z, o.z * alpha);
        o.w = fmaf(ex, vt.w, o.w * alpha);
        m = mn;
    }

    float inv = 1.0f / (lsum + 1e-16f);   // deg=0 -> o=0 -> writes 0
    float4 r = make_float4(o.x * inv, o.y * inv, o.z * inv, o.w * inv);
    *(float4*)&out[(size_t)n * DIMX + 4 * lane] = r;
}

// ---------------------------------------------------------------------------
extern "C" void kernel_launch(void* const* d_in, const int* in_sizes, int n_in,
                              void* d_out, int out_size, void* d_ws, size_t ws_size,
                              hipStream_t stream)
{
    const float* x    = (const float*)d_in[0];
    const int*   ei   = (const int*)d_in[1];     // int32! harness converts int64 -> int
    const float* ea   = (const float*)d_in[2];
    const float* Wqkv = (const float*)d_in[3];
    const float* bqkv = (const float*)d_in[4];
    const float* Wk   = (const float*)d_in[5];
    const float* bk   = (const float*)d_in[6];
    const float* Wq   = (const float*)d_in[7];
    const float* bq   = (const float*)d_in[8];

    int Nn = in_sizes[0] / DIMX;
    int E  = in_sizes[1] / 2;
    float* out = (float*)d_out;

    // workspace layout
    float* qkv  = (float*)d_ws;                          // Nn*512 floats (102.4 MB)
    int*   deg  = (int*)d_ws + (size_t)Nn * QKVW;        // Nn
    int*   cur  = deg + Nn;                              // Nn
    int*   off  = cur + Nn;                              // Nn+1
    int2*  elist = (int2*)(off + ((Nn + 2) & ~1));       // E int2, 8B-aligned

    hipMemsetAsync(deg, 0, sizeof(int) * 2 * (size_t)Nn, stream);  // deg + cur

    qkv_gemm<<<dim3((Nn + 127) / 128, QKVW / 64), 256, 0, stream>>>(x, Wqkv, bqkv, qkv, Nn);
    count_kernel<<<(E + 255) / 256, 256, 0, stream>>>(ei, deg, E);
    scan_kernel<<<1, 1024, 0, stream>>>(deg, off, Nn);
    scatter_kernel<<<(E + 255) / 256, 256, 0, stream>>>(ei, off, cur, elist, E);
    node_attn<<<(Nn + 3) / 4, 256, 0, stream>>>(qkv, elist, off, ea, Wq, bq, Wk, bk, out, Nn);
}